// Round 10
// baseline (231.828 us; speedup 1.0000x reference)
//
#include <hip/hip_runtime.h>
#include <hip/hip_bf16.h>

#define NN 50000
#define EE 800000
#define FIN 256
#define FH 128
#define FO 16
#define MAXDEG 64
#define SCB (EE / 256)          // 3125 scatter blocks
#define G1B ((NN + 127) / 128)  // 391 gemm1 blocks

using short8 = __attribute__((ext_vector_type(8))) short;
using f32x4  = __attribute__((ext_vector_type(4))) float;

__device__ __forceinline__ unsigned short f2b(float f) {
    unsigned int u = __float_as_uint(f);
    u += 0x7fffu + ((u >> 16) & 1u);   // round-to-nearest-even
    return (unsigned short)(u >> 16);
}
__device__ __forceinline__ float b2f(unsigned short h) {
    return __uint_as_float(((unsigned int)h) << 16);
}

// ---------- prep: detect ei dtype + zero cursors + transpose/convert weights ----------
__global__ void prep_k(const unsigned int* __restrict__ ei, int* __restrict__ flag,
                       int* __restrict__ cursor,
                       const float* __restrict__ W1, const float* __restrict__ W2,
                       unsigned short* __restrict__ w1t, unsigned short* __restrict__ w2t) {
    int i = blockIdx.x * 256 + threadIdx.x;
    if (blockIdx.x == 0 && threadIdx.x < 64) {
        unsigned int v = (threadIdx.x < 32) ? ei[2 * threadIdx.x + 1] : 0u;
        unsigned long long ball = __ballot(v != 0u);
        if (threadIdx.x == 0) *flag = (ball == 0ull) ? 1 : 0;
    }
    if (i < NN) cursor[i] = 0;
    if (i < FH * FIN) {
        int n = i / FIN, k = i % FIN;
        w1t[i] = f2b(W1[k * FH + n]);
    }
    if (i < FO * FH) {
        int n = i / FH, k = i % FH;
        w2t[i] = f2b(W2[k * FO + n]);
    }
}

__device__ __forceinline__ void decode_edge(const void* ei, int int64flag, int e,
                                            int& r, int& c) {
    if (int64flag) {
        const long long* p = (const long long*)ei;
        r = (int)p[e]; c = (int)p[EE + e];
    } else {
        const int* p = (const int*)ei;
        r = p[e]; c = p[EE + e];
    }
    r = min(max(r, 0), NN - 1);
    c = min(max(c, 0), NN - 1);
}

// ---------- fused: scatter blocks [0,SCB) || gemm1 blocks [SCB, SCB+G1B) ----------
// scatter: padj[c*64+pos] = (r<<16) | bf16(ew)      (1 atomic per edge)
// gemm1:   h1lin = bf16(x @ W1)  (raw, no dinv)     (MFMA 16x16x32)
__global__ __launch_bounds__(256) void fused_k(const void* __restrict__ ei,
                                               const float* __restrict__ ew,
                                               const int* __restrict__ flag,
                                               int* __restrict__ cursor,
                                               unsigned int* __restrict__ padj,
                                               const float* __restrict__ X,
                                               const unsigned short* __restrict__ Bt,
                                               unsigned short* __restrict__ C) {
    if (blockIdx.x < SCB) {
        int e = blockIdx.x * 256 + threadIdx.x;
        int r, c;
        decode_edge(ei, *flag, e, r, c);
        float w = ew[e];
        int pos = atomicAdd(&cursor[c], 1);
        if (pos < MAXDEG)
            padj[c * MAXDEG + pos] = ((unsigned int)r << 16) | (unsigned int)f2b(w);
        return;
    }
    // ---- gemm1 path ----
    const int bx = blockIdx.x - SCB;
    const int lane = threadIdx.x & 63;
    const int wave = threadIdx.x >> 6;
    const int m0 = bx * 128 + wave * 32;
    const int lr = lane & 15;
    const int lk = (lane >> 4) * 8;
    f32x4 acc[2][8];
#pragma unroll
    for (int i = 0; i < 2; i++)
#pragma unroll
        for (int j = 0; j < 8; j++) acc[i][j] = (f32x4){0.f, 0.f, 0.f, 0.f};

    for (int k0 = 0; k0 < FIN; k0 += 32) {
        short8 a[2], b[8];
#pragma unroll
        for (int mi = 0; mi < 2; mi++) {
            int row = m0 + mi * 16 + lr;
            if (row >= NN) row = NN - 1;               // clamp (in-bounds, discarded)
            const float* ap = X + (size_t)row * FIN + k0 + lk;
            float4 v0 = *(const float4*)ap;
            float4 v1 = *(const float4*)(ap + 4);
            a[mi][0] = (short)f2b(v0.x); a[mi][1] = (short)f2b(v0.y);
            a[mi][2] = (short)f2b(v0.z); a[mi][3] = (short)f2b(v0.w);
            a[mi][4] = (short)f2b(v1.x); a[mi][5] = (short)f2b(v1.y);
            a[mi][6] = (short)f2b(v1.z); a[mi][7] = (short)f2b(v1.w);
        }
#pragma unroll
        for (int ni = 0; ni < 8; ni++)
            b[ni] = *(const short8*)(Bt + (ni * 16 + lr) * FIN + k0 + lk);
#pragma unroll
        for (int mi = 0; mi < 2; mi++)
#pragma unroll
            for (int ni = 0; ni < 8; ni++)
                acc[mi][ni] = __builtin_amdgcn_mfma_f32_16x16x32_bf16(
                    a[mi], b[ni], acc[mi][ni], 0, 0, 0);
    }
    const int r0 = (lane >> 4) * 4;
#pragma unroll
    for (int mi = 0; mi < 2; mi++)
#pragma unroll
        for (int r = 0; r < 4; r++) {
            int row = m0 + mi * 16 + r0 + r;
            if (row < NN) {
#pragma unroll
                for (int ni = 0; ni < 8; ni++)
                    C[(size_t)row * FH + ni * 16 + lr] = f2b(acc[mi][ni][r]);
            }
        }
}

// ---------- deg = segmented sum of ew over padded rows; dinv = rsqrt ----------
__global__ __launch_bounds__(256) void deg_k(const int* __restrict__ cursor,
                                             const unsigned int* __restrict__ padj,
                                             float* __restrict__ dinv) {
    const int n = blockIdx.x * 16 + (threadIdx.x >> 4);   // grid exact: 3125*16
    const int f = threadIdx.x & 15;
    const int cnt = min(cursor[n], MAXDEG);
    const unsigned int* base = padj + n * MAXDEG;
    float s = 0.f;
    for (int j = f; j < cnt; j += 16) s += b2f((unsigned short)(base[j] & 0xffff));
#pragma unroll
    for (int d = 1; d < 16; d <<= 1) s += __shfl_xor(s, d);
    if (f == 0) dinv[n] = (s > 0.f) ? rsqrtf(s) : 0.f;
}

// ---------- rewrite: padj weight <- bf16(dinv_c * ew * dinv_r)  (full norm) ----------
__global__ void rewrite_k(const int* __restrict__ cursor, const float* __restrict__ dinv,
                          unsigned int* __restrict__ padj) {
    int i = blockIdx.x * 256 + threadIdx.x;     // over NN*MAXDEG
    int n = i >> 6, j = i & 63;
    if (n >= NN) return;
    if (j < min(cursor[n], MAXDEG)) {
        unsigned int u = padj[i];
        int r = u >> 16;
        float w = b2f((unsigned short)(u & 0xffff));
        float nw = dinv[n] * w * dinv[r];
        padj[i] = (u & 0xffff0000u) | (unsigned int)f2b(nw);
    }
}

// ---------- agg1: h1 = relu(sum_e nw*h1lin[r] + b1), one wave/node ----------
__global__ __launch_bounds__(256) void agg1_k(const int* __restrict__ cursor,
                                              const unsigned int* __restrict__ padj,
                                              const unsigned short* __restrict__ hlin,
                                              const float* __restrict__ bias1,
                                              unsigned short* __restrict__ h1) {
    const int wid = blockIdx.x * 4 + (threadIdx.x >> 6);   // node id (grid exact)
    const int lane = threadIdx.x & 63;
    const int cnt = min(__builtin_amdgcn_readfirstlane(cursor[wid]), MAXDEG);
    const unsigned int* base = padj + wid * MAXDEG;
    const unsigned short* hp = hlin + 2 * lane;

    float a0 = 0.f, a1 = 0.f, b0 = 0.f, b1v = 0.f;
    float c0 = 0.f, c1 = 0.f, d0 = 0.f, d1 = 0.f;
    int j = 0;
    for (; j + 4 <= cnt; j += 4) {
        unsigned int u0 = base[j + 0], u1 = base[j + 1];
        unsigned int u2 = base[j + 2], u3 = base[j + 3];
        unsigned int g0 = *(const unsigned int*)(hp + (size_t)(u0 >> 16) * FH);
        unsigned int g1 = *(const unsigned int*)(hp + (size_t)(u1 >> 16) * FH);
        unsigned int g2 = *(const unsigned int*)(hp + (size_t)(u2 >> 16) * FH);
        unsigned int g3 = *(const unsigned int*)(hp + (size_t)(u3 >> 16) * FH);
        float n0 = b2f((unsigned short)(u0 & 0xffff));
        float n1 = b2f((unsigned short)(u1 & 0xffff));
        float n2 = b2f((unsigned short)(u2 & 0xffff));
        float n3 = b2f((unsigned short)(u3 & 0xffff));
        a0  += n0 * b2f((unsigned short)(g0 & 0xffff));
        a1  += n0 * b2f((unsigned short)(g0 >> 16));
        b0  += n1 * b2f((unsigned short)(g1 & 0xffff));
        b1v += n1 * b2f((unsigned short)(g1 >> 16));
        c0  += n2 * b2f((unsigned short)(g2 & 0xffff));
        c1  += n2 * b2f((unsigned short)(g2 >> 16));
        d0  += n3 * b2f((unsigned short)(g3 & 0xffff));
        d1  += n3 * b2f((unsigned short)(g3 >> 16));
    }
    for (; j < cnt; j++) {
        unsigned int u = base[j];
        unsigned int g = *(const unsigned int*)(hp + (size_t)(u >> 16) * FH);
        float n = b2f((unsigned short)(u & 0xffff));
        a0 += n * b2f((unsigned short)(g & 0xffff));
        a1 += n * b2f((unsigned short)(g >> 16));
    }
    float r0 = ((a0 + b0) + (c0 + d0)) + bias1[2 * lane];
    float r1 = ((a1 + b1v) + (c1 + d1)) + bias1[2 * lane + 1];
    unsigned int w = (unsigned int)f2b(fmaxf(r0, 0.f)) |
                     ((unsigned int)f2b(fmaxf(r1, 0.f)) << 16);
    *(unsigned int*)(h1 + (size_t)wid * FH + 2 * lane) = w;
}

// ---------- GEMM2: h1 bf16 [NN,128] x w2t -> h2lin bf16 [NN,16] ----------
__global__ __launch_bounds__(256) void gemm2_k(const unsigned short* __restrict__ A,
                                               const unsigned short* __restrict__ Bt,
                                               unsigned short* __restrict__ C) {
    const int lane = threadIdx.x & 63;
    const int wave = threadIdx.x >> 6;
    const int m0 = blockIdx.x * 128 + wave * 32;
    const int lr = lane & 15;
    const int lk = (lane >> 4) * 8;
    f32x4 acc[2];
    acc[0] = (f32x4){0.f, 0.f, 0.f, 0.f};
    acc[1] = (f32x4){0.f, 0.f, 0.f, 0.f};

    for (int k0 = 0; k0 < FH; k0 += 32) {
        short8 a[2], b;
#pragma unroll
        for (int mi = 0; mi < 2; mi++) {
            int row = m0 + mi * 16 + lr;
            if (row >= NN) row = NN - 1;
            a[mi] = *(const short8*)(A + (size_t)row * FH + k0 + lk);
        }
        b = *(const short8*)(Bt + lr * FH + k0 + lk);
#pragma unroll
        for (int mi = 0; mi < 2; mi++)
            acc[mi] = __builtin_amdgcn_mfma_f32_16x16x32_bf16(a[mi], b, acc[mi], 0, 0, 0);
    }
    const int r0 = (lane >> 4) * 4;
#pragma unroll
    for (int mi = 0; mi < 2; mi++)
#pragma unroll
        for (int r = 0; r < 4; r++) {
            int row = m0 + mi * 16 + r0 + r;
            if (row < NN) C[(size_t)row * FO + lr] = f2b(acc[mi][r]);
        }
}

// ---------- agg2: out = log_softmax(sum_e nw*h2lin[r] + b2) ----------
__global__ __launch_bounds__(256) void agg2_k(const int* __restrict__ cursor,
                                              const unsigned int* __restrict__ padj,
                                              const unsigned short* __restrict__ h2lin,
                                              const float* __restrict__ bias2,
                                              float* __restrict__ out) {
    const int g = threadIdx.x >> 4, f = threadIdx.x & 15;
    const int n = blockIdx.x * 16 + g;                     // grid exact
    const int cnt = min(cursor[n], MAXDEG);
    const unsigned int* base = padj + n * MAXDEG;
    float a0 = 0.f, a1 = 0.f, a2 = 0.f, a3 = 0.f;
    int j = 0;
    for (; j + 4 <= cnt; j += 4) {
        unsigned int u0 = base[j + 0], u1 = base[j + 1];
        unsigned int u2 = base[j + 2], u3 = base[j + 3];
        float v0 = b2f(h2lin[(size_t)(u0 >> 16) * FO + f]);
        float v1 = b2f(h2lin[(size_t)(u1 >> 16) * FO + f]);
        float v2 = b2f(h2lin[(size_t)(u2 >> 16) * FO + f]);
        float v3 = b2f(h2lin[(size_t)(u3 >> 16) * FO + f]);
        a0 += b2f((unsigned short)(u0 & 0xffff)) * v0;
        a1 += b2f((unsigned short)(u1 & 0xffff)) * v1;
        a2 += b2f((unsigned short)(u2 & 0xffff)) * v2;
        a3 += b2f((unsigned short)(u3 & 0xffff)) * v3;
    }
    for (; j < cnt; j++) {
        unsigned int u = base[j];
        a0 += b2f((unsigned short)(u & 0xffff)) * b2f(h2lin[(size_t)(u >> 16) * FO + f]);
    }
    float acc = ((a0 + a1) + (a2 + a3)) + bias2[f];
    float m = acc;
#pragma unroll
    for (int d = 1; d < 16; d <<= 1) m = fmaxf(m, __shfl_xor(m, d));
    float ex = expf(acc - m);
    float sum = ex;
#pragma unroll
    for (int d = 1; d < 16; d <<= 1) sum += __shfl_xor(sum, d);
    out[(size_t)n * FO + f] = acc - m - logf(sum);
}

extern "C" void kernel_launch(void* const* d_in, const int* in_sizes, int n_in,
                              void* d_out, int out_size, void* d_ws, size_t ws_size,
                              hipStream_t stream) {
    const float* x  = (const float*)d_in[0];
    const void*  ei = d_in[1];
    const float* ew = (const float*)d_in[2];
    const float* W1 = (const float*)d_in[3];
    const float* b1 = (const float*)d_in[4];
    const float* W2 = (const float*)d_in[5];
    const float* b2 = (const float*)d_in[6];
    float* out = (float*)d_out;

    // workspace carve-up (256B aligned); total ~41 MB
    char* base = (char*)d_ws;
    size_t off = 0;
    auto alloc = [&](size_t bytes) {
        void* p = base + off;
        off += (bytes + 255) & ~(size_t)255;
        return p;
    };
    int*          flag   = (int*)alloc(4);
    int*          cursor = (int*)alloc(NN * 4);
    float*        dinv   = (float*)alloc(NN * 4);
    unsigned int* padj   = (unsigned int*)alloc((size_t)NN * MAXDEG * 4);  // 12.8 MB
    unsigned short* w1t   = (unsigned short*)alloc(FH * FIN * 2);
    unsigned short* w2t   = (unsigned short*)alloc(FO * FH * 2);
    unsigned short* h1lin = (unsigned short*)alloc((size_t)NN * FH * 2);
    unsigned short* h1    = (unsigned short*)alloc((size_t)NN * FH * 2);
    unsigned short* h2lin = (unsigned short*)alloc((size_t)NN * FO * 2);
    (void)ws_size; (void)n_in; (void)in_sizes; (void)out_size;

    const int NB = (NN + 255) / 256;  // 196

    prep_k<<<NB, 256, 0, stream>>>((const unsigned int*)ei, flag, cursor, W1, W2, w1t, w2t);
    fused_k<<<SCB + G1B, 256, 0, stream>>>(ei, ew, flag, cursor, padj, x, w1t, h1lin);
    deg_k<<<NN / 16, 256, 0, stream>>>(cursor, padj, dinv);
    rewrite_k<<<NN * MAXDEG / 256, 256, 0, stream>>>(cursor, dinv, padj);
    agg1_k<<<NN / 4, 256, 0, stream>>>(cursor, padj, h1lin, b1, h1);
    gemm2_k<<<(NN + 127) / 128, 256, 0, stream>>>(h1, w2t, h2lin);
    agg2_k<<<NN / 16, 256, 0, stream>>>(cursor, padj, h2lin, b2, out);
}

// Round 11
// 217.912 us; speedup vs baseline: 1.0639x; 1.0639x over previous
//
#include <hip/hip_runtime.h>
#include <hip/hip_bf16.h>

#define NN 50000
#define EE 800000
#define FIN 256
#define FH 128
#define FO 16
#define MAXDEG 64

using short8 = __attribute__((ext_vector_type(8))) short;
using f32x4  = __attribute__((ext_vector_type(4))) float;

__device__ __forceinline__ unsigned short f2b(float f) {
    unsigned int u = __float_as_uint(f);
    u += 0x7fffu + ((u >> 16) & 1u);   // round-to-nearest-even
    return (unsigned short)(u >> 16);
}
__device__ __forceinline__ float b2f(unsigned short h) {
    return __uint_as_float(((unsigned int)h) << 16);
}

// ---------- prep: detect ei dtype + zero cursors + transpose/convert weights ----------
__global__ void prep_k(const unsigned int* __restrict__ ei, int* __restrict__ flag,
                       int* __restrict__ cursor,
                       const float* __restrict__ W1, const float* __restrict__ W2,
                       unsigned short* __restrict__ w1t, unsigned short* __restrict__ w2t) {
    int i = blockIdx.x * 256 + threadIdx.x;
    if (blockIdx.x == 0 && threadIdx.x < 64) {
        unsigned int v = (threadIdx.x < 32) ? ei[2 * threadIdx.x + 1] : 0u;
        unsigned long long ball = __ballot(v != 0u);
        if (threadIdx.x == 0) *flag = (ball == 0ull) ? 1 : 0;
    }
    if (i < NN) cursor[i] = 0;
    if (i < FH * FIN) {
        int n = i / FIN, k = i % FIN;
        w1t[i] = f2b(W1[k * FH + n]);
    }
    if (i < FO * FH) {
        int n = i / FH, k = i % FH;
        w2t[i] = f2b(W2[k * FO + n]);
    }
}

__device__ __forceinline__ void decode_edge(const void* ei, int int64flag, int e,
                                            int& r, int& c) {
    if (int64flag) {
        const long long* p = (const long long*)ei;
        r = (int)p[e]; c = (int)p[EE + e];
    } else {
        const int* p = (const int*)ei;
        r = p[e]; c = p[EE + e];
    }
    r = min(max(r, 0), NN - 1);
    c = min(max(c, 0), NN - 1);
}

// ---------- one-pass padded-CSR build: 1 atomic per edge ----------
// entry = (row << 16) | bf16(edge_weight)
__global__ void scatterpad_k(const void* __restrict__ ei, const float* __restrict__ ew,
                             const int* __restrict__ flag, int* __restrict__ cursor,
                             unsigned int* __restrict__ padj) {
    int e = blockIdx.x * 256 + threadIdx.x;
    if (e >= EE) return;
    int r, c;
    decode_edge(ei, *flag, e, r, c);
    float w = ew[e];
    int pos = atomicAdd(&cursor[c], 1);
    if (pos < MAXDEG)
        padj[c * MAXDEG + pos] = ((unsigned int)r << 16) | (unsigned int)f2b(w);
}

// ---------- deg = segmented sum of ew over padded rows; dinv = rsqrt ----------
__global__ __launch_bounds__(256) void deg_k(const int* __restrict__ cursor,
                                             const unsigned int* __restrict__ padj,
                                             float* __restrict__ dinv) {
    const int n = blockIdx.x * 16 + (threadIdx.x >> 4);   // grid exact: 3125*16
    const int f = threadIdx.x & 15;
    const int cnt = min(cursor[n], MAXDEG);
    const unsigned int* base = padj + n * MAXDEG;
    float s = 0.f;
    for (int j = f; j < cnt; j += 16) s += b2f((unsigned short)(base[j] & 0xffff));
#pragma unroll
    for (int d = 1; d < 16; d <<= 1) s += __shfl_xor(s, d);
    if (f == 0) dinv[n] = (s > 0.f) ? rsqrtf(s) : 0.f;
}

// ---------- GEMM1: x f32 [NN,256] x w1t -> h1lin bf16 [NN,128], rows scaled by dinv ----------
__global__ __launch_bounds__(256) void gemm1_k(const float* __restrict__ X,
                                               const unsigned short* __restrict__ Bt,
                                               const float* __restrict__ dinv,
                                               unsigned short* __restrict__ C) {
    const int lane = threadIdx.x & 63;
    const int wave = threadIdx.x >> 6;
    const int m0 = blockIdx.x * 128 + wave * 32;
    const int lr = lane & 15;
    const int lk = (lane >> 4) * 8;
    f32x4 acc[2][8];
#pragma unroll
    for (int i = 0; i < 2; i++)
#pragma unroll
        for (int j = 0; j < 8; j++) acc[i][j] = (f32x4){0.f, 0.f, 0.f, 0.f};

    for (int k0 = 0; k0 < FIN; k0 += 32) {
        short8 a[2], b[8];
#pragma unroll
        for (int mi = 0; mi < 2; mi++) {
            int row = m0 + mi * 16 + lr;
            if (row >= NN) row = NN - 1;               // clamp (in-bounds, discarded)
            const float* ap = X + (size_t)row * FIN + k0 + lk;
            float4 v0 = *(const float4*)ap;
            float4 v1 = *(const float4*)(ap + 4);
            a[mi][0] = (short)f2b(v0.x); a[mi][1] = (short)f2b(v0.y);
            a[mi][2] = (short)f2b(v0.z); a[mi][3] = (short)f2b(v0.w);
            a[mi][4] = (short)f2b(v1.x); a[mi][5] = (short)f2b(v1.y);
            a[mi][6] = (short)f2b(v1.z); a[mi][7] = (short)f2b(v1.w);
        }
#pragma unroll
        for (int ni = 0; ni < 8; ni++)
            b[ni] = *(const short8*)(Bt + (ni * 16 + lr) * FIN + k0 + lk);
#pragma unroll
        for (int mi = 0; mi < 2; mi++)
#pragma unroll
            for (int ni = 0; ni < 8; ni++)
                acc[mi][ni] = __builtin_amdgcn_mfma_f32_16x16x32_bf16(
                    a[mi], b[ni], acc[mi][ni], 0, 0, 0);
    }
    const int r0 = (lane >> 4) * 4;
#pragma unroll
    for (int mi = 0; mi < 2; mi++)
#pragma unroll
        for (int r = 0; r < 4; r++) {
            int row = m0 + mi * 16 + r0 + r;
            if (row < NN) {
                float dv = dinv[row];
#pragma unroll
                for (int ni = 0; ni < 8; ni++)
                    C[(size_t)row * FH + ni * 16 + lr] = f2b(acc[mi][ni][r] * dv);
            }
        }
}

// ---------- GEMM2: h1 bf16 [NN,128] x w2t -> h2lin bf16 [NN,16], rows scaled by dinv ----------
__global__ __launch_bounds__(256) void gemm2_k(const unsigned short* __restrict__ A,
                                               const unsigned short* __restrict__ Bt,
                                               const float* __restrict__ dinv,
                                               unsigned short* __restrict__ C) {
    const int lane = threadIdx.x & 63;
    const int wave = threadIdx.x >> 6;
    const int m0 = blockIdx.x * 128 + wave * 32;
    const int lr = lane & 15;
    const int lk = (lane >> 4) * 8;
    f32x4 acc[2];
    acc[0] = (f32x4){0.f, 0.f, 0.f, 0.f};
    acc[1] = (f32x4){0.f, 0.f, 0.f, 0.f};

    for (int k0 = 0; k0 < FH; k0 += 32) {
        short8 a[2], b;
#pragma unroll
        for (int mi = 0; mi < 2; mi++) {
            int row = m0 + mi * 16 + lr;
            if (row >= NN) row = NN - 1;
            a[mi] = *(const short8*)(A + (size_t)row * FH + k0 + lk);
        }
        b = *(const short8*)(Bt + lr * FH + k0 + lk);
#pragma unroll
        for (int mi = 0; mi < 2; mi++)
            acc[mi] = __builtin_amdgcn_mfma_f32_16x16x32_bf16(a[mi], b, acc[mi], 0, 0, 0);
    }
    const int r0 = (lane >> 4) * 4;
#pragma unroll
    for (int mi = 0; mi < 2; mi++)
#pragma unroll
        for (int r = 0; r < 4; r++) {
            int row = m0 + mi * 16 + r0 + r;
            if (row < NN) {
                float dv = dinv[row];
                C[(size_t)row * FO + lr] = f2b(acc[mi][r] * dv);
            }
        }
}

// ---------- agg1: h1 = relu(dinv_c * sum_e ew*h1lin'[r] + b1), one wave/node, unroll x8 ----------
__global__ __launch_bounds__(256) void agg1_k(const int* __restrict__ cursor,
                                              const unsigned int* __restrict__ padj,
                                              const unsigned short* __restrict__ hlin,
                                              const float* __restrict__ dinv,
                                              const float* __restrict__ bias1,
                                              unsigned short* __restrict__ h1) {
    const int wid = blockIdx.x * 4 + (threadIdx.x >> 6);   // node id (grid exact)
    const int lane = threadIdx.x & 63;
    const int cnt = min(__builtin_amdgcn_readfirstlane(cursor[wid]), MAXDEG);
    const unsigned int* base = padj + wid * MAXDEG;
    const unsigned short* hp = hlin + 2 * lane;

    float s0[8], s1[8];
#pragma unroll
    for (int k = 0; k < 8; k++) { s0[k] = 0.f; s1[k] = 0.f; }

    int j = 0;
    for (; j + 8 <= cnt; j += 8) {
        unsigned int u[8], g[8];
#pragma unroll
        for (int k = 0; k < 8; k++) u[k] = base[j + k];
#pragma unroll
        for (int k = 0; k < 8; k++)
            g[k] = *(const unsigned int*)(hp + (size_t)(u[k] >> 16) * FH);
#pragma unroll
        for (int k = 0; k < 8; k++) {
            float n = b2f((unsigned short)(u[k] & 0xffff));
            s0[k] += n * b2f((unsigned short)(g[k] & 0xffff));
            s1[k] += n * b2f((unsigned short)(g[k] >> 16));
        }
    }
    for (; j + 4 <= cnt; j += 4) {
        unsigned int u[4], g[4];
#pragma unroll
        for (int k = 0; k < 4; k++) u[k] = base[j + k];
#pragma unroll
        for (int k = 0; k < 4; k++)
            g[k] = *(const unsigned int*)(hp + (size_t)(u[k] >> 16) * FH);
#pragma unroll
        for (int k = 0; k < 4; k++) {
            float n = b2f((unsigned short)(u[k] & 0xffff));
            s0[k] += n * b2f((unsigned short)(g[k] & 0xffff));
            s1[k] += n * b2f((unsigned short)(g[k] >> 16));
        }
    }
    for (; j < cnt; j++) {
        unsigned int u = base[j];
        unsigned int g = *(const unsigned int*)(hp + (size_t)(u >> 16) * FH);
        float n = b2f((unsigned short)(u & 0xffff));
        s0[0] += n * b2f((unsigned short)(g & 0xffff));
        s1[0] += n * b2f((unsigned short)(g >> 16));
    }
    float r0 = ((s0[0] + s0[1]) + (s0[2] + s0[3])) + ((s0[4] + s0[5]) + (s0[6] + s0[7]));
    float r1 = ((s1[0] + s1[1]) + (s1[2] + s1[3])) + ((s1[4] + s1[5]) + (s1[6] + s1[7]));
    float dc = dinv[wid];
    r0 = dc * r0 + bias1[2 * lane];
    r1 = dc * r1 + bias1[2 * lane + 1];
    unsigned int w = (unsigned int)f2b(fmaxf(r0, 0.f)) |
                     ((unsigned int)f2b(fmaxf(r1, 0.f)) << 16);
    *(unsigned int*)(h1 + (size_t)wid * FH + 2 * lane) = w;
}

// ---------- agg2: out = log_softmax(dinv_c * sum_e ew*h2lin'[r] + b2), unroll x8 ----------
__global__ __launch_bounds__(256) void agg2_k(const int* __restrict__ cursor,
                                              const unsigned int* __restrict__ padj,
                                              const unsigned short* __restrict__ h2lin,
                                              const float* __restrict__ dinv,
                                              const float* __restrict__ bias2,
                                              float* __restrict__ out) {
    const int g = threadIdx.x >> 4, f = threadIdx.x & 15;
    const int n = blockIdx.x * 16 + g;                     // grid exact
    const int cnt = min(cursor[n], MAXDEG);
    const unsigned int* base = padj + n * MAXDEG;
    float s[8];
#pragma unroll
    for (int k = 0; k < 8; k++) s[k] = 0.f;

    int j = 0;
    for (; j + 8 <= cnt; j += 8) {
        unsigned int u[8];
        float v[8];
#pragma unroll
        for (int k = 0; k < 8; k++) u[k] = base[j + k];
#pragma unroll
        for (int k = 0; k < 8; k++) v[k] = b2f(h2lin[(size_t)(u[k] >> 16) * FO + f]);
#pragma unroll
        for (int k = 0; k < 8; k++) s[k] += b2f((unsigned short)(u[k] & 0xffff)) * v[k];
    }
    for (; j + 4 <= cnt; j += 4) {
        unsigned int u[4];
        float v[4];
#pragma unroll
        for (int k = 0; k < 4; k++) u[k] = base[j + k];
#pragma unroll
        for (int k = 0; k < 4; k++) v[k] = b2f(h2lin[(size_t)(u[k] >> 16) * FO + f]);
#pragma unroll
        for (int k = 0; k < 4; k++) s[k] += b2f((unsigned short)(u[k] & 0xffff)) * v[k];
    }
    for (; j < cnt; j++) {
        unsigned int u = base[j];
        s[0] += b2f((unsigned short)(u & 0xffff)) * b2f(h2lin[(size_t)(u >> 16) * FO + f]);
    }
    float acc = ((s[0] + s[1]) + (s[2] + s[3])) + ((s[4] + s[5]) + (s[6] + s[7]));
    acc = dinv[n] * acc + bias2[f];
    float m = acc;
#pragma unroll
    for (int d = 1; d < 16; d <<= 1) m = fmaxf(m, __shfl_xor(m, d));
    float ex = expf(acc - m);
    float sum = ex;
#pragma unroll
    for (int d = 1; d < 16; d <<= 1) sum += __shfl_xor(sum, d);
    out[(size_t)n * FO + f] = acc - m - logf(sum);
}

extern "C" void kernel_launch(void* const* d_in, const int* in_sizes, int n_in,
                              void* d_out, int out_size, void* d_ws, size_t ws_size,
                              hipStream_t stream) {
    const float* x  = (const float*)d_in[0];
    const void*  ei = d_in[1];
    const float* ew = (const float*)d_in[2];
    const float* W1 = (const float*)d_in[3];
    const float* b1 = (const float*)d_in[4];
    const float* W2 = (const float*)d_in[5];
    const float* b2 = (const float*)d_in[6];
    float* out = (float*)d_out;

    // workspace carve-up (256B aligned); total ~41 MB
    char* base = (char*)d_ws;
    size_t off = 0;
    auto alloc = [&](size_t bytes) {
        void* p = base + off;
        off += (bytes + 255) & ~(size_t)255;
        return p;
    };
    int*          flag   = (int*)alloc(4);
    int*          cursor = (int*)alloc(NN * 4);
    float*        dinv   = (float*)alloc(NN * 4);
    unsigned int* padj   = (unsigned int*)alloc((size_t)NN * MAXDEG * 4);  // 12.8 MB
    unsigned short* w1t   = (unsigned short*)alloc(FH * FIN * 2);
    unsigned short* w2t   = (unsigned short*)alloc(FO * FH * 2);
    unsigned short* h1lin = (unsigned short*)alloc((size_t)NN * FH * 2);
    unsigned short* h1    = (unsigned short*)alloc((size_t)NN * FH * 2);
    unsigned short* h2lin = (unsigned short*)alloc((size_t)NN * FO * 2);
    (void)ws_size; (void)n_in; (void)in_sizes; (void)out_size;

    const int NB = (NN + 255) / 256;  // 196

    prep_k<<<NB, 256, 0, stream>>>((const unsigned int*)ei, flag, cursor, W1, W2, w1t, w2t);
    scatterpad_k<<<EE / 256, 256, 0, stream>>>(ei, ew, flag, cursor, padj);
    deg_k<<<NN / 16, 256, 0, stream>>>(cursor, padj, dinv);

    gemm1_k<<<(NN + 127) / 128, 256, 0, stream>>>(x, w1t, dinv, h1lin);
    agg1_k<<<NN / 4, 256, 0, stream>>>(cursor, padj, h1lin, dinv, b1, h1);
    gemm2_k<<<(NN + 127) / 128, 256, 0, stream>>>(h1, w2t, dinv, h2lin);
    agg2_k<<<NN / 16, 256, 0, stream>>>(cursor, padj, h2lin, dinv, b2, out);
}

// Round 14
// 193.422 us; speedup vs baseline: 1.1986x; 1.1266x over previous
//
#include <hip/hip_runtime.h>
#include <hip/hip_bf16.h>

#define NN 50000
#define EE 800000
#define FIN 256
#define FH 128
#define FO 16
#define MAXDEG 64
#define NBKT 196          // buckets of 256 nodes (col >> 8)
#define BCAP 5120         // per-bucket edge capacity (mean 4096, sigma ~64)
#define EPB 2048          // edges per part_k block
#define PB ((EE + EPB - 1) / EPB)   // 391

using short8 = __attribute__((ext_vector_type(8))) short;
using f32x4  = __attribute__((ext_vector_type(4))) float;

__device__ __forceinline__ unsigned short f2b(float f) {
    unsigned int u = __float_as_uint(f);
    u += 0x7fffu + ((u >> 16) & 1u);   // round-to-nearest-even
    return (unsigned short)(u >> 16);
}
__device__ __forceinline__ float b2f(unsigned short h) {
    return __uint_as_float(((unsigned int)h) << 16);
}

// ---------- prep: detect ei dtype + zero bucket cursors + transpose/convert weights ----------
__global__ void prep_k(const unsigned int* __restrict__ ei, int* __restrict__ flag,
                       int* __restrict__ bcur,
                       const float* __restrict__ W1, const float* __restrict__ W2,
                       unsigned short* __restrict__ w1t, unsigned short* __restrict__ w2t) {
    int i = blockIdx.x * 256 + threadIdx.x;
    if (blockIdx.x == 0 && threadIdx.x < 64) {
        unsigned int v = (threadIdx.x < 32) ? ei[2 * threadIdx.x + 1] : 0u;
        unsigned long long ball = __ballot(v != 0u);
        if (threadIdx.x == 0) *flag = (ball == 0ull) ? 1 : 0;
    }
    if (i < NBKT * 16) bcur[i] = 0;       // 64B-padded cursors
    if (i < FH * FIN) {
        int n = i / FIN, k = i % FIN;
        w1t[i] = f2b(W1[k * FH + n]);
    }
    if (i < FO * FH) {
        int n = i / FH, k = i % FH;
        w2t[i] = f2b(W2[k * FO + n]);
    }
}

__device__ __forceinline__ void decode_edge(const void* ei, int int64flag, int e,
                                            int& r, int& c) {
    if (int64flag) {
        const long long* p = (const long long*)ei;
        r = (int)p[e]; c = (int)p[EE + e];
    } else {
        const int* p = (const int*)ei;
        r = p[e]; c = p[EE + e];
    }
    r = min(max(r, 0), NN - 1);
    c = min(max(c, 0), NN - 1);
}

// ---------- pass 1: partition edges into 196 col-range buckets (dense 8B writes) ----------
__global__ __launch_bounds__(256) void part_k(const void* __restrict__ ei,
                                              const float* __restrict__ ew,
                                              const int* __restrict__ flag,
                                              int* __restrict__ bcur,
                                              uint2* __restrict__ part) {
    __shared__ int hist[NBKT];
    __shared__ int lcur[NBKT];
    const int t = threadIdx.x;
    const int e0 = blockIdx.x * EPB;
    for (int i = t; i < NBKT; i += 256) hist[i] = 0;
    __syncthreads();

    const int fl = *flag;
    int r[8], c[8], bk[8];
    float w[8];
#pragma unroll
    for (int k = 0; k < 8; k++) {
        int e = e0 + k * 256 + t;
        if (e < EE) {
            decode_edge(ei, fl, e, r[k], c[k]);
            w[k] = ew[e];
            bk[k] = c[k] >> 8;
            atomicAdd(&hist[bk[k]], 1);
        } else bk[k] = -1;
    }
    __syncthreads();
    if (t < NBKT) {
        int h = hist[t];
        lcur[t] = (h > 0) ? atomicAdd(&bcur[t * 16], h) : 0;
    }
    __syncthreads();
#pragma unroll
    for (int k = 0; k < 8; k++) {
        if (bk[k] >= 0) {
            int pos = atomicAdd(&lcur[bk[k]], 1);
            if (pos < BCAP)
                part[(size_t)bk[k] * BCAP + pos] =
                    make_uint2(((unsigned int)r[k] << 16) | (unsigned int)c[k],
                               __float_as_uint(w[k]));
        }
    }
}

// ---------- pass 2: per-bucket padded-CSR build in LDS + deg/dinv, coalesced writeout ----------
__global__ __launch_bounds__(256) void build_k(const int* __restrict__ bcur,
                                               const uint2* __restrict__ part,
                                               unsigned int* __restrict__ padj,
                                               int* __restrict__ cursor,
                                               float* __restrict__ dinv) {
    __shared__ int cnt[256];
    __shared__ unsigned int staged[256 * MAXDEG];   // 64 KB
    const int b = blockIdx.x, t = threadIdx.x;
    cnt[t] = 0;
    __syncthreads();

    const int ecnt = min(bcur[b * 16], BCAP);
    const uint2* src = part + (size_t)b * BCAP;
    for (int j = t; j < ecnt; j += 256) {
        uint2 e = src[j];
        int cl = (int)(e.x & 0xffff) - (b << 8);     // 0..255
        int pos = atomicAdd(&cnt[cl], 1);
        if (pos < MAXDEG)
            staged[cl * MAXDEG + pos] =
                (e.x & 0xffff0000u) | (unsigned int)f2b(__uint_as_float(e.y));
    }
    __syncthreads();

    const int n = (b << 8) + t;
    if (n < NN) {
        int cc = min(cnt[t], MAXDEG);
        cursor[n] = cc;
        float s = 0.f;
        for (int j = 0; j < cc; j++)
            s += b2f((unsigned short)(staged[t * MAXDEG + j] & 0xffff));
        dinv[n] = (s > 0.f) ? rsqrtf(s) : 0.f;
    }
    const size_t obase = (size_t)b * 256 * MAXDEG;
    for (int idx = t; idx < 256 * MAXDEG; idx += 256)
        padj[obase + idx] = staged[idx];
}

// ---------- GEMM1: x f32 [NN,256] x w1t -> h1lin bf16 [NN,128], rows scaled by dinv ----------
__global__ __launch_bounds__(256) void gemm1_k(const float* __restrict__ X,
                                               const unsigned short* __restrict__ Bt,
                                               const float* __restrict__ dinv,
                                               unsigned short* __restrict__ C) {
    const int lane = threadIdx.x & 63;
    const int wave = threadIdx.x >> 6;
    const int m0 = blockIdx.x * 128 + wave * 32;
    const int lr = lane & 15;
    const int lk = (lane >> 4) * 8;
    f32x4 acc[2][8];
#pragma unroll
    for (int i = 0; i < 2; i++)
#pragma unroll
        for (int j = 0; j < 8; j++) acc[i][j] = (f32x4){0.f, 0.f, 0.f, 0.f};

    for (int k0 = 0; k0 < FIN; k0 += 32) {
        short8 a[2], b[8];
#pragma unroll
        for (int mi = 0; mi < 2; mi++) {
            int row = m0 + mi * 16 + lr;
            if (row >= NN) row = NN - 1;               // clamp (in-bounds, discarded)
            const float* ap = X + (size_t)row * FIN + k0 + lk;
            float4 v0 = *(const float4*)ap;
            float4 v1 = *(const float4*)(ap + 4);
            a[mi][0] = (short)f2b(v0.x); a[mi][1] = (short)f2b(v0.y);
            a[mi][2] = (short)f2b(v0.z); a[mi][3] = (short)f2b(v0.w);
            a[mi][4] = (short)f2b(v1.x); a[mi][5] = (short)f2b(v1.y);
            a[mi][6] = (short)f2b(v1.z); a[mi][7] = (short)f2b(v1.w);
        }
#pragma unroll
        for (int ni = 0; ni < 8; ni++)
            b[ni] = *(const short8*)(Bt + (ni * 16 + lr) * FIN + k0 + lk);
#pragma unroll
        for (int mi = 0; mi < 2; mi++)
#pragma unroll
            for (int ni = 0; ni < 8; ni++)
                acc[mi][ni] = __builtin_amdgcn_mfma_f32_16x16x32_bf16(
                    a[mi], b[ni], acc[mi][ni], 0, 0, 0);
    }
    const int r0 = (lane >> 4) * 4;
#pragma unroll
    for (int mi = 0; mi < 2; mi++)
#pragma unroll
        for (int r = 0; r < 4; r++) {
            int row = m0 + mi * 16 + r0 + r;
            if (row < NN) {
                float dv = dinv[row];
#pragma unroll
                for (int ni = 0; ni < 8; ni++)
                    C[(size_t)row * FH + ni * 16 + lr] = f2b(acc[mi][ni][r] * dv);
            }
        }
}

// ---------- GEMM2: h1 bf16 [NN,128] x w2t -> h2lin bf16 [NN,16], rows scaled by dinv ----------
__global__ __launch_bounds__(256) void gemm2_k(const unsigned short* __restrict__ A,
                                               const unsigned short* __restrict__ Bt,
                                               const float* __restrict__ dinv,
                                               unsigned short* __restrict__ C) {
    const int lane = threadIdx.x & 63;
    const int wave = threadIdx.x >> 6;
    const int m0 = blockIdx.x * 128 + wave * 32;
    const int lr = lane & 15;
    const int lk = (lane >> 4) * 8;
    f32x4 acc[2];
    acc[0] = (f32x4){0.f, 0.f, 0.f, 0.f};
    acc[1] = (f32x4){0.f, 0.f, 0.f, 0.f};

    for (int k0 = 0; k0 < FH; k0 += 32) {
        short8 a[2], b;
#pragma unroll
        for (int mi = 0; mi < 2; mi++) {
            int row = m0 + mi * 16 + lr;
            if (row >= NN) row = NN - 1;
            a[mi] = *(const short8*)(A + (size_t)row * FH + k0 + lk);
        }
        b = *(const short8*)(Bt + lr * FH + k0 + lk);
#pragma unroll
        for (int mi = 0; mi < 2; mi++)
            acc[mi] = __builtin_amdgcn_mfma_f32_16x16x32_bf16(a[mi], b, acc[mi], 0, 0, 0);
    }
    const int r0 = (lane >> 4) * 4;
#pragma unroll
    for (int mi = 0; mi < 2; mi++)
#pragma unroll
        for (int r = 0; r < 4; r++) {
            int row = m0 + mi * 16 + r0 + r;
            if (row < NN) {
                float dv = dinv[row];
                C[(size_t)row * FO + lr] = f2b(acc[mi][r] * dv);
            }
        }
}

// ---------- agg1: h1 = relu(dinv_c * sum_e ew*h1lin'[r] + b1), one wave/node, unroll x8 ----------
__global__ __launch_bounds__(256) void agg1_k(const int* __restrict__ cursor,
                                              const unsigned int* __restrict__ padj,
                                              const unsigned short* __restrict__ hlin,
                                              const float* __restrict__ dinv,
                                              const float* __restrict__ bias1,
                                              unsigned short* __restrict__ h1) {
    const int wid = blockIdx.x * 4 + (threadIdx.x >> 6);   // node id (grid exact)
    const int lane = threadIdx.x & 63;
    const int cnt = min(__builtin_amdgcn_readfirstlane(cursor[wid]), MAXDEG);
    const unsigned int* base = padj + (size_t)wid * MAXDEG;
    const unsigned short* hp = hlin + 2 * lane;

    float s0[8], s1[8];
#pragma unroll
    for (int k = 0; k < 8; k++) { s0[k] = 0.f; s1[k] = 0.f; }

    int j = 0;
    for (; j + 8 <= cnt; j += 8) {
        unsigned int u[8], g[8];
#pragma unroll
        for (int k = 0; k < 8; k++) u[k] = base[j + k];
#pragma unroll
        for (int k = 0; k < 8; k++)
            g[k] = *(const unsigned int*)(hp + (size_t)(u[k] >> 16) * FH);
#pragma unroll
        for (int k = 0; k < 8; k++) {
            float n = b2f((unsigned short)(u[k] & 0xffff));
            s0[k] += n * b2f((unsigned short)(g[k] & 0xffff));
            s1[k] += n * b2f((unsigned short)(g[k] >> 16));
        }
    }
    for (; j + 4 <= cnt; j += 4) {
        unsigned int u[4], g[4];
#pragma unroll
        for (int k = 0; k < 4; k++) u[k] = base[j + k];
#pragma unroll
        for (int k = 0; k < 4; k++)
            g[k] = *(const unsigned int*)(hp + (size_t)(u[k] >> 16) * FH);
#pragma unroll
        for (int k = 0; k < 4; k++) {
            float n = b2f((unsigned short)(u[k] & 0xffff));
            s0[k] += n * b2f((unsigned short)(g[k] & 0xffff));
            s1[k] += n * b2f((unsigned short)(g[k] >> 16));
        }
    }
    for (; j < cnt; j++) {
        unsigned int u = base[j];
        unsigned int g = *(const unsigned int*)(hp + (size_t)(u >> 16) * FH);
        float n = b2f((unsigned short)(u & 0xffff));
        s0[0] += n * b2f((unsigned short)(g & 0xffff));
        s1[0] += n * b2f((unsigned short)(g >> 16));
    }
    float r0 = ((s0[0] + s0[1]) + (s0[2] + s0[3])) + ((s0[4] + s0[5]) + (s0[6] + s0[7]));
    float r1 = ((s1[0] + s1[1]) + (s1[2] + s1[3])) + ((s1[4] + s1[5]) + (s1[6] + s1[7]));
    float dc = dinv[wid];
    r0 = dc * r0 + bias1[2 * lane];
    r1 = dc * r1 + bias1[2 * lane + 1];
    unsigned int w = (unsigned int)f2b(fmaxf(r0, 0.f)) |
                     ((unsigned int)f2b(fmaxf(r1, 0.f)) << 16);
    *(unsigned int*)(h1 + (size_t)wid * FH + 2 * lane) = w;
}

// ---------- agg2: out = log_softmax(dinv_c * sum_e ew*h2lin'[r] + b2), unroll x8 ----------
__global__ __launch_bounds__(256) void agg2_k(const int* __restrict__ cursor,
                                              const unsigned int* __restrict__ padj,
                                              const unsigned short* __restrict__ h2lin,
                                              const float* __restrict__ dinv,
                                              const float* __restrict__ bias2,
                                              float* __restrict__ out) {
    const int g = threadIdx.x >> 4, f = threadIdx.x & 15;
    const int n = blockIdx.x * 16 + g;                     // grid exact
    const int cnt = min(cursor[n], MAXDEG);
    const unsigned int* base = padj + (size_t)n * MAXDEG;
    float s[8];
#pragma unroll
    for (int k = 0; k < 8; k++) s[k] = 0.f;

    int j = 0;
    for (; j + 8 <= cnt; j += 8) {
        unsigned int u[8];
        float v[8];
#pragma unroll
        for (int k = 0; k < 8; k++) u[k] = base[j + k];
#pragma unroll
        for (int k = 0; k < 8; k++) v[k] = b2f(h2lin[(size_t)(u[k] >> 16) * FO + f]);
#pragma unroll
        for (int k = 0; k < 8; k++) s[k] += b2f((unsigned short)(u[k] & 0xffff)) * v[k];
    }
    for (; j + 4 <= cnt; j += 4) {
        unsigned int u[4];
        float v[4];
#pragma unroll
        for (int k = 0; k < 4; k++) u[k] = base[j + k];
#pragma unroll
        for (int k = 0; k < 4; k++) v[k] = b2f(h2lin[(size_t)(u[k] >> 16) * FO + f]);
#pragma unroll
        for (int k = 0; k < 4; k++) s[k] += b2f((unsigned short)(u[k] & 0xffff)) * v[k];
    }
    for (; j < cnt; j++) {
        unsigned int u = base[j];
        s[0] += b2f((unsigned short)(u & 0xffff)) * b2f(h2lin[(size_t)(u >> 16) * FO + f]);
    }
    float acc = ((s[0] + s[1]) + (s[2] + s[3])) + ((s[4] + s[5]) + (s[6] + s[7]));
    acc = dinv[n] * acc + bias2[f];
    float m = acc;
#pragma unroll
    for (int d = 1; d < 16; d <<= 1) m = fmaxf(m, __shfl_xor(m, d));
    float ex = expf(acc - m);
    float sum = ex;
#pragma unroll
    for (int d = 1; d < 16; d <<= 1) sum += __shfl_xor(sum, d);
    out[(size_t)n * FO + f] = acc - m - logf(sum);
}

extern "C" void kernel_launch(void* const* d_in, const int* in_sizes, int n_in,
                              void* d_out, int out_size, void* d_ws, size_t ws_size,
                              hipStream_t stream) {
    const float* x  = (const float*)d_in[0];
    const void*  ei = d_in[1];
    const float* ew = (const float*)d_in[2];
    const float* W1 = (const float*)d_in[3];
    const float* b1 = (const float*)d_in[4];
    const float* W2 = (const float*)d_in[5];
    const float* b2 = (const float*)d_in[6];
    float* out = (float*)d_out;

    // workspace carve-up (256B aligned); total ~41.5 MB (part aliases h1lin)
    char* base = (char*)d_ws;
    size_t off = 0;
    auto alloc = [&](size_t bytes) {
        void* p = base + off;
        off += (bytes + 255) & ~(size_t)255;
        return p;
    };
    int*          flag   = (int*)alloc(4);
    int*          bcur   = (int*)alloc((size_t)NBKT * 16 * 4);       // 64B-padded cursors
    int*          cursor = (int*)alloc(NN * 4);
    float*        dinv   = (float*)alloc(NN * 4);
    unsigned int* padj   = (unsigned int*)alloc((size_t)NBKT * 256 * MAXDEG * 4); // 12.85 MB
    unsigned short* w1t   = (unsigned short*)alloc(FH * FIN * 2);
    unsigned short* w2t   = (unsigned short*)alloc(FO * FH * 2);
    unsigned short* h1lin = (unsigned short*)alloc((size_t)NN * FH * 2);
    unsigned short* h1    = (unsigned short*)alloc((size_t)NN * FH * 2);
    unsigned short* h2lin = (unsigned short*)alloc((size_t)NN * FO * 2);
    // part (196*5120*8 = 8.03 MB) aliases h1lin (12.8 MB): part dead before gemm1 writes h1lin
    uint2* part = (uint2*)h1lin;
    (void)ws_size; (void)n_in; (void)in_sizes; (void)out_size;

    const int NB = (NN + 255) / 256;  // 196

    prep_k<<<NB, 256, 0, stream>>>((const unsigned int*)ei, flag, bcur, W1, W2, w1t, w2t);
    part_k<<<PB, 256, 0, stream>>>(ei, ew, flag, bcur, part);
    build_k<<<NBKT, 256, 0, stream>>>(bcur, part, padj, cursor, dinv);

    gemm1_k<<<(NN + 127) / 128, 256, 0, stream>>>(x, w1t, dinv, h1lin);
    agg1_k<<<NN / 4, 256, 0, stream>>>(cursor, padj, h1lin, dinv, b1, h1);
    gemm2_k<<<(NN + 127) / 128, 256, 0, stream>>>(h1, w2t, dinv, h2lin);
    agg2_k<<<NN / 16, 256, 0, stream>>>(cursor, padj, h2lin, dinv, b2, out);
}